// Round 20
// baseline (370.817 us; speedup 1.0000x reference)
//
#include <hip/hip_runtime.h>
#include <hip/hip_bf16.h>
#include <math.h>

#define Bc 4
#define Sc 2048
#define Dc 1024
#define Hc 16
#define DKc 64
#define DFFc 4096
#define Mc (Bc*Sc)
#define LN_EPS 1e-6f

typedef unsigned short ushort_t;
typedef short bf16x8 __attribute__((ext_vector_type(8)));
typedef float f32x4 __attribute__((ext_vector_type(4)));
typedef float f32x16 __attribute__((ext_vector_type(16)));

typedef __attribute__((address_space(3))) void lds_void_t;
typedef __attribute__((address_space(1))) const void gconst_void_t;

__device__ __forceinline__ void gload_lds16(const void* g, void* l) {
  __builtin_amdgcn_global_load_lds((gconst_void_t*)g, (lds_void_t*)l, 16, 0, 0);
}

__device__ __forceinline__ ushort_t f2bf(float f) {
  union { float f; unsigned int u; } a; a.f = f;
  unsigned int r = a.u + 0x7fffu + ((a.u >> 16) & 1u);
  return (ushort_t)(r >> 16);
}

__device__ __forceinline__ float rcpf(float x) { return __builtin_amdgcn_rcpf(x); }

__device__ __forceinline__ void swapl(unsigned& a, unsigned& b) {
  asm("v_permlane32_swap_b32 %0, %1" : "+v"(a), "+v"(b));
}
__device__ __forceinline__ unsigned cvtpk_bf16(float lo, float hi) {
  unsigned r;
  asm("v_cvt_pk_bf16_f32 %0, %1, %2" : "=v"(r) : "v"(lo), "v"(hi));
  return r;
}

// ---------------- weight transpose + f32->bf16 convert ----------------
__global__ __launch_bounds__(256) void k_transpose_cvt(
    const float* __restrict__ W, ushort_t* __restrict__ WT, int K, int N) {
  __shared__ float t[32][33];
  const int tx = threadIdx.x & 31, ty = threadIdx.x >> 5;
  const int n0 = blockIdx.x * 32, k0 = blockIdx.y * 32;
#pragma unroll
  for (int i = 0; i < 4; ++i)
    t[ty + i * 8][tx] = W[(size_t)(k0 + ty + i * 8) * N + n0 + tx];
  __syncthreads();
#pragma unroll
  for (int i = 0; i < 4; ++i)
    WT[(size_t)(n0 + ty + i * 8) * K + k0 + tx] = f2bf(t[tx][ty + i * 8]);
}

// ---------------- layernorm ----------------
__global__ __launch_bounds__(256) void k_layernorm(
    const float* __restrict__ x, const float* __restrict__ alpha,
    const float* __restrict__ beta, ushort_t* __restrict__ out) {
  const int row = blockIdx.x;
  const int tid = threadIdx.x;
  const int w = tid >> 6, lane = tid & 63;
  const float4 v = ((const float4*)(x + (size_t)row * Dc))[tid];
  float s = v.x + v.y + v.z + v.w;
#pragma unroll
  for (int m = 32; m >= 1; m >>= 1) s += __shfl_xor(s, m, 64);
  __shared__ float ws[8];
  if (lane == 0) ws[w] = s;
  __syncthreads();
  s = ws[0] + ws[1] + ws[2] + ws[3];
  const float mean = s * (1.0f / Dc);
  const float dx = v.x - mean, dy = v.y - mean, dz = v.z - mean, dw = v.w - mean;
  float ss = dx * dx + dy * dy + dz * dz + dw * dw;
#pragma unroll
  for (int m = 32; m >= 1; m >>= 1) ss += __shfl_xor(ss, m, 64);
  if (lane == 0) ws[4 + w] = ss;
  __syncthreads();
  ss = ws[4] + ws[5] + ws[6] + ws[7];
  const float stdv = sqrtf(ss / (float)(Dc - 1));
  const float inv = 1.0f / (stdv + LN_EPS);
  const float4 a = ((const float4*)alpha)[tid];
  const float4 b = ((const float4*)beta)[tid];
  uint2 o;
  o.x = cvtpk_bf16(a.x * dx * inv + b.x, a.y * dy * inv + b.y);
  o.y = cvtpk_bf16(a.z * dz * inv + b.z, a.w * dw * inv + b.w);
  *(uint2*)(out + (size_t)row * Dc + tid * 4) = o;
}

// ---------------- mask compaction ----------------
__global__ __launch_bounds__(256) void k_compact(const int* __restrict__ mask,
                                                 int* __restrict__ cidx,
                                                 float* __restrict__ cmadd,
                                                 int* __restrict__ ntile) {
  const int b = blockIdx.x;
  const int tid = threadIdx.x;
  const int base = b * Sc;
  for (int i = tid; i < Sc; i += 256) cmadd[base + i] = -1.442695041e9f;
  int mloc[8];
  int cnt = 0;
#pragma unroll
  for (int j = 0; j < 8; ++j) {
    mloc[j] = mask[base + tid * 8 + j];
    cnt += mloc[j];
  }
  __shared__ int ps[256];
  ps[tid] = cnt;
  __syncthreads();
  for (int ofs = 1; ofs < 256; ofs <<= 1) {
    const int v = (tid >= ofs) ? ps[tid - ofs] : 0;
    __syncthreads();
    ps[tid] += v;
    __syncthreads();
  }
  const int total = ps[255];
  int run = tid ? ps[tid - 1] : 0;
#pragma unroll
  for (int j = 0; j < 8; ++j) {
    const int gi = base + tid * 8 + j;
    if (mloc[j]) {
      cidx[gi] = run;
      cmadd[base + run] = -8.0f;
      run++;
    } else {
      cidx[gi] = -1;
    }
  }
  if (tid == 0) {
    int nt = (total + 31) >> 5;
    ntile[b] = nt < 1 ? 1 : nt;
  }
}

// ---- bf16 GEMM v2 (3-buffer; QKV/FFN0; M-banded XCD; lean epilogues) ----
template <int MODE>
__global__ __launch_bounds__(512, 4) void k_gemm8(
    const ushort_t* __restrict__ A, const ushort_t* __restrict__ BT,
    const float* __restrict__ bias, const float* __restrict__ bias2,
    const float* __restrict__ bias3, const float* __restrict__ resid,
    const int* __restrict__ cidx,
    void* __restrict__ Cout, void* __restrict__ Cout2, void* __restrict__ Cout3,
    int N, int K, int nxn /*unused*/) {
  __shared__ __align__(16) ushort_t As[3][256 * 32];
  __shared__ __align__(16) ushort_t Bs[3][128 * 32];
  const int tid = threadIdx.x;
  const int lane = tid & 63;
  const int wid = tid >> 6;
  const int wm = wid >> 1, wn = wid & 1;
  const int lrow = lane & 15, lgrp = lane >> 4;
  const int xcd = blockIdx.x & 7;
  const int idx = blockIdx.x >> 3;
  const int im = xcd * 4 + (idx & 3);
  const int in_ = idx >> 2;
  const int m0 = im << 8, n0 = in_ << 7;

  const f32x4 zero4 = {0.f, 0.f, 0.f, 0.f};
  f32x4 acc[4][4];
#pragma unroll
  for (int i = 0; i < 4; ++i)
#pragma unroll
    for (int j = 0; j < 4; ++j) acc[i][j] = zero4;

  const int ar0 = tid >> 2;
  const int as0 = (tid & 3) ^ ((ar0 >> 1) & 3);
  const int ar1 = ar0 + 128;
  const ushort_t* Ag0 = A + (size_t)(m0 + ar0) * K + as0 * 8;
  const ushort_t* Ag1 = A + (size_t)(m0 + ar1) * K + as0 * 8;
  const ushort_t* Bg0 = BT + (size_t)(n0 + ar0 % 128) * K + as0 * 8;
  char* const a_w = (char*)(&As[0][0]) + wid * 1024;
  char* const b_w = (char*)(&Bs[0][0]) + wid * 1024;

  const int sl = lgrp ^ ((lrow >> 1) & 3);
  const int aoff = (wm * 64 + lrow) * 32 + sl * 8;
  const int boff = (wn * 64 + lrow) * 32 + sl * 8;

  const int nk = K >> 5;
  {
    gload_lds16(Ag0, a_w);
    gload_lds16(Ag1, a_w + 8192);
    gload_lds16(Bg0, b_w);
    gload_lds16(Ag0 + 32, a_w + 16384);
    gload_lds16(Ag1 + 32, a_w + 16384 + 8192);
    gload_lds16(Bg0 + 32, b_w + 8192);
  }
  int cur = 0;
  for (int t = 0; t < nk; ++t) {
    if (t + 1 < nk) { asm volatile("s_waitcnt vmcnt(3)" ::: "memory"); }
    else            { asm volatile("s_waitcnt vmcnt(0)" ::: "memory"); }
    asm volatile("s_barrier" ::: "memory");
    const ushort_t* Ab = &As[cur][0];
    const ushort_t* Bb = &Bs[cur][0];
    bf16x8 af[4], bf[4];
#pragma unroll
    for (int mf = 0; mf < 4; ++mf) af[mf] = *(const bf16x8*)(Ab + aoff + mf * 512);
#pragma unroll
    for (int nf = 0; nf < 4; ++nf) bf[nf] = *(const bf16x8*)(Bb + boff + nf * 512);
    if (t + 2 < nk) {
      const int bi = (cur + 2 >= 3) ? cur - 1 : cur + 2;
      const size_t ko = (size_t)(t + 2) * 32;
      gload_lds16(Ag0 + ko, a_w + bi * 16384);
      gload_lds16(Ag1 + ko, a_w + bi * 16384 + 8192);
      gload_lds16(Bg0 + ko, b_w + bi * 8192);
    }
    __builtin_amdgcn_s_setprio(1);
#pragma unroll
    for (int mf = 0; mf < 4; ++mf)
#pragma unroll
      for (int nf = 0; nf < 4; ++nf)
        acc[mf][nf] = __builtin_amdgcn_mfma_f32_16x16x32_bf16(af[mf], bf[nf], acc[mf][nf], 0, 0, 0);
    __builtin_amdgcn_s_setprio(0);
    asm volatile("s_barrier" ::: "memory");
    cur = (cur + 1 == 3) ? 0 : cur + 1;
  }

  const float* bsrc = bias;
  int n0l = n0;
  int seg = 0;
  if (MODE == 4) {
    seg = n0 >> 10;
    n0l = n0 & 1023;
    bsrc = (seg == 0) ? bias : (seg == 1 ? bias2 : bias3);
  }
  float bv[4];
#pragma unroll
  for (int n = 0; n < 4; ++n) bv[n] = bsrc[n0l + wn * 64 + n * 16 + lrow];

  const int gb = m0 >> 11;

#pragma unroll
  for (int m = 0; m < 4; ++m) {
    int cpv[4];
    if (MODE == 4 && seg >= 1) {
#pragma unroll
      for (int r = 0; r < 4; ++r)
        cpv[r] = cidx[m0 + wm * 64 + m * 16 + lgrp * 4 + r];
    }
#pragma unroll
    for (int n = 0; n < 4; ++n) {
      const int col = (MODE == 4 ? n0l : n0) + wn * 64 + n * 16 + lrow;
      if (MODE == 4 && seg == 2) {
        const int hh = col >> 6, dd = col & 63;
        ushort_t* Cv = (ushort_t*)Cout3 + ((size_t)(gb * Hc + hh) * DKc + dd) * Sc;
#pragma unroll
        for (int r = 0; r < 4; r += 2) {
          const unsigned wpk = cvtpk_bf16(acc[m][n][r] + bv[n], acc[m][n][r + 1] + bv[n]);
          if (cpv[r] >= 0) Cv[cpv[r]] = (ushort_t)wpk;
          if (cpv[r + 1] >= 0) Cv[cpv[r + 1]] = (ushort_t)(wpk >> 16);
        }
      } else if (MODE == 4 && seg == 1) {
        ushort_t* Ck = (ushort_t*)Cout2 + (size_t)gb * Sc * Dc + col;
#pragma unroll
        for (int r = 0; r < 4; r += 2) {
          const unsigned wpk = cvtpk_bf16(acc[m][n][r] + bv[n], acc[m][n][r + 1] + bv[n]);
          if (cpv[r] >= 0) Ck[(size_t)cpv[r] * Dc] = (ushort_t)wpk;
          if (cpv[r + 1] >= 0) Ck[(size_t)cpv[r + 1] * Dc] = (ushort_t)(wpk >> 16);
        }
      } else if (MODE == 4) {
        ushort_t* Co = (ushort_t*)Cout;
        const size_t row0 = (size_t)(m0 + wm * 64 + m * 16 + lgrp * 4);
#pragma unroll
        for (int r = 0; r < 4; r += 2) {
          const unsigned wpk = cvtpk_bf16(acc[m][n][r] + bv[n], acc[m][n][r + 1] + bv[n]);
          Co[(row0 + r) * Dc + col] = (ushort_t)wpk;
          Co[(row0 + r + 1) * Dc + col] = (ushort_t)(wpk >> 16);
        }
      } else if (MODE == 2) {
        const size_t row0 = (size_t)(m0 + wm * 64 + m * 16 + lgrp * 4);
#pragma unroll
        for (int r = 0; r < 4; r += 2) {
          float v0 = acc[m][n][r] + bv[n];
          float v1 = acc[m][n][r + 1] + bv[n];
          v0 = v0 * rcpf(1.0f + exp2f(-2.4554669f * v0));
          v1 = v1 * rcpf(1.0f + exp2f(-2.4554669f * v1));
          const unsigned wpk = cvtpk_bf16(v0, v1);
          ((ushort_t*)Cout)[(row0 + r) * N + col] = (ushort_t)wpk;
          ((ushort_t*)Cout)[(row0 + r + 1) * N + col] = (ushort_t)(wpk >> 16);
        }
      } else {
#pragma unroll
        for (int r = 0; r < 4; ++r) {
          const size_t row = (size_t)(m0 + wm * 64 + m * 16 + lgrp * 4 + r);
          const float v = acc[m][n][r] + bv[n] + resid[row * N + col];
          ((float*)Cout)[row * N + col] = v;
        }
      }
    }
  }
}

// ---- bf16 GEMM v5 "deep": 4 LDS buffers (96KB), prefetch depth 3 tiles ----
// For the 1-block/CU MODE-1 GEMMs (O-proj, FFN1): they were staging-LATENCY
// bound (1570cy/iter vs 308cy MFMA; vmcnt(3) waits on ~500-900cy L3/HBM loads
// with no co-resident block to hide them). Depth-3 prefetch (~2000cy cover)
// hides worst-case latency. Same algebra/swizzle as k_gemm8; stage t+3 into
// (cur+3)&3, whose reads completed pre-barrier at iter t-1 (same proof).
// Tail: vmcnt 6 -> 3 -> 0. f32 + resid epilogue only.
__global__ __launch_bounds__(512, 2) void k_gemm8d(
    const ushort_t* __restrict__ A, const ushort_t* __restrict__ BT,
    const float* __restrict__ bias, const float* __restrict__ resid,
    float* __restrict__ Cout, int N, int K) {
  __shared__ __align__(16) ushort_t As[4][256 * 32];  // 64KB
  __shared__ __align__(16) ushort_t Bs[4][128 * 32];  // 32KB (96KB total)
  const int tid = threadIdx.x;
  const int lane = tid & 63;
  const int wid = tid >> 6;
  const int wm = wid >> 1, wn = wid & 1;
  const int lrow = lane & 15, lgrp = lane >> 4;
  const int xcd = blockIdx.x & 7;
  const int idx = blockIdx.x >> 3;
  const int im = xcd * 4 + (idx & 3);   // M-band
  const int in_ = idx >> 2;
  const int m0 = im << 8, n0 = in_ << 7;

  const f32x4 zero4 = {0.f, 0.f, 0.f, 0.f};
  f32x4 acc[4][4];
#pragma unroll
  for (int i = 0; i < 4; ++i)
#pragma unroll
    for (int j = 0; j < 4; ++j) acc[i][j] = zero4;

  const int ar0 = tid >> 2;
  const int as0 = (tid & 3) ^ ((ar0 >> 1) & 3);
  const int ar1 = ar0 + 128;
  const ushort_t* Ag0 = A + (size_t)(m0 + ar0) * K + as0 * 8;
  const ushort_t* Ag1 = A + (size_t)(m0 + ar1) * K + as0 * 8;
  const ushort_t* Bg0 = BT + (size_t)(n0 + ar0 % 128) * K + as0 * 8;
  char* const a_w = (char*)(&As[0][0]) + wid * 1024;   // + bi*16384 (+8192 sweep1)
  char* const b_w = (char*)(&Bs[0][0]) + wid * 1024;   // + bi*8192

  const int sl = lgrp ^ ((lrow >> 1) & 3);
  const int aoff = (wm * 64 + lrow) * 32 + sl * 8;
  const int boff = (wn * 64 + lrow) * 32 + sl * 8;

  const int nk = K >> 5;
  // prologue: stage tiles 0,1,2 (9 loads/thread in flight)
#pragma unroll
  for (int tt = 0; tt < 3; ++tt) {
    const size_t ko = (size_t)tt * 32;
    gload_lds16(Ag0 + ko, a_w + tt * 16384);
    gload_lds16(Ag1 + ko, a_w + tt * 16384 + 8192);
    gload_lds16(Bg0 + ko, b_w + tt * 8192);
  }
  int cur = 0;
  for (int t = 0; t < nk; ++t) {
    if (t + 2 < nk)      { asm volatile("s_waitcnt vmcnt(6)" ::: "memory"); }
    else if (t + 1 < nk) { asm volatile("s_waitcnt vmcnt(3)" ::: "memory"); }
    else                 { asm volatile("s_waitcnt vmcnt(0)" ::: "memory"); }
    asm volatile("s_barrier" ::: "memory");   // tile t resident for all waves
    const ushort_t* Ab = &As[cur][0];
    const ushort_t* Bb = &Bs[cur][0];
    bf16x8 af[4], bf[4];
#pragma unroll
    for (int mf = 0; mf < 4; ++mf) af[mf] = *(const bf16x8*)(Ab + aoff + mf * 512);
#pragma unroll
    for (int nf = 0; nf < 4; ++nf) bf[nf] = *(const bf16x8*)(Bb + boff + nf * 512);
    if (t + 3 < nk) {                         // stage t+3 (buf freed at t-1)
      const int bi = (cur + 3) & 3;
      const size_t ko = (size_t)(t + 3) * 32;
      gload_lds16(Ag0 + ko, a_w + bi * 16384);
      gload_lds16(Ag1 + ko, a_w + bi * 16384 + 8192);
      gload_lds16(Bg0 + ko, b_w + bi * 8192);
    }
    __builtin_amdgcn_s_setprio(1);
#pragma unroll
    for (int mf = 0; mf < 4; ++mf)
#pragma unroll
      for (int nf = 0; nf < 4; ++nf)
        acc[mf][nf] = __builtin_amdgcn_mfma_f32_16x16x32_bf16(af[mf], bf[nf], acc[mf][nf], 0, 0, 0);
    __builtin_amdgcn_s_setprio(0);
    asm volatile("s_barrier" ::: "memory");   // reads of buf[cur] drained
    cur = (cur + 1) & 3;
  }

  float bv[4];
#pragma unroll
  for (int n = 0; n < 4; ++n) bv[n] = bias[n0 + wn * 64 + n * 16 + lrow];
#pragma unroll
  for (int m = 0; m < 4; ++m)
#pragma unroll
    for (int n = 0; n < 4; ++n)
#pragma unroll
      for (int r = 0; r < 4; ++r) {
        const size_t row = (size_t)(m0 + wm * 64 + m * 16 + lgrp * 4 + r);
        const size_t col = (size_t)(n0 + wn * 64 + n * 16 + lrow);
        Cout[row * N + col] = acc[m][n][r] + bv[n] + resid[row * N + col];
      }
}

// ---- flash attention v12 (unchanged) ----
#define KSCALE 0.1803368801e0f  /* 0.125 * log2(e) */
__global__ __launch_bounds__(512) void k_attn12(
    const ushort_t* __restrict__ Qb, const ushort_t* __restrict__ Kb,
    const ushort_t* __restrict__ Vt, const float* __restrict__ madd,
    const int* __restrict__ ntile, ushort_t* __restrict__ Ob) {
  __shared__ __align__(16) ushort_t Ks[4][32 * 64];
  __shared__ __align__(16) ushort_t Vs[4][64 * 32];
  __shared__ __align__(16) float Ms[Sc];

  const int bid = blockIdx.x;
  const int xcd = bid & 7, idx = bid >> 3;
  const int bh = xcd * 8 + (idx >> 3);
  const int qb = idx & 7;
  const int b = bh >> 4, h = bh & 15;
  const int nt = ntile[b];
  const int tid = threadIdx.x;
  const int lane = tid & 63, w = tid >> 6;
  const int l31 = lane & 31, hi = lane >> 5;
  const size_t bS = (size_t)b * Sc;
  const int qrow0 = qb * 256 + w * 32;

  bf16x8 qf[4];
  const ushort_t* qp = Qb + (bS + qrow0 + l31) * Dc + h * DKc + hi * 8;
#pragma unroll
  for (int c = 0; c < 4; ++c) qf[c] = *(const bf16x8*)(qp + c * 16);

  bf16x8 ones;
#pragma unroll
  for (int i = 0; i < 8; ++i) ones[i] = (short)0x3F80;

  f32x16 accA, accB, accS;
#pragma unroll
  for (int i = 0; i < 16; ++i) { accA[i] = 0.f; accB[i] = 0.f; accS[i] = 0.f; }

  const ushort_t* Vth = Vt + (size_t)bh * (DKc * Sc);
  const float* mp = madd + b * Sc;

  const int c0 = tid & 255;
  const int kr = c0 >> 3, ksl = (c0 & 7) ^ (kr & 7);
  const int vr = c0 >> 2, vsl = (c0 & 3) ^ ((vr >> 1) & 3);
  const ushort_t* Kg = Kb + (bS + kr) * Dc + h * DKc + ksl * 8;
  const ushort_t* Vg = Vth + (size_t)vr * Sc + vsl * 8;
  char* const k_w = (char*)(&Ks[0][0]) + (w & 3) * 1024;
  char* const v_w = (char*)(&Vs[0][0]) + (w & 3) * 1024;

  gload_lds16(mp + tid * 4, (char*)Ms + w * 1024);
  if (w < 4) {
    gload_lds16(Kg, k_w);
    gload_lds16(Kg + (size_t)32 * Dc, k_w + 4096);
  } else {
    gload_lds16(Vg, v_w);
    gload_lds16(Vg + 32, v_w + 4096);
  }

  const int vsw = (l31 >> 1) & 3;
  int cur = 0;
  f32x16 scA, scB;

  auto qk_phase = [&](f32x16& scN, int t) {
    const char* Kbuf = (const char*)(&Ks[cur][0]);
    bf16x8 kf[4];
#pragma unroll
    for (int c = 0; c < 4; ++c) {
      const int slr = (c * 2 + hi) ^ (l31 & 7);
      kf[c] = *(const bf16x8*)(Kbuf + l31 * 128 + slr * 16);
    }
    if (t + 2 < 64) {
      const int bi = (cur + 2) & 3;
      const size_t kv2 = (size_t)(t + 2) * 32;
      if (w < 4) gload_lds16(Kg + kv2 * Dc, k_w + bi * 4096);
      else       gload_lds16(Vg + kv2, v_w + bi * 4096);
    }
#pragma unroll
    for (int i = 0; i < 16; ++i) scN[i] = 0.f;
    __builtin_amdgcn_s_setprio(1);
    scN = __builtin_amdgcn_mfma_f32_32x32x16_bf16(kf[0], qf[0], scN, 0, 0, 0);
    scN = __builtin_amdgcn_mfma_f32_32x32x16_bf16(kf[1], qf[1], scN, 0, 0, 0);
    scN = __builtin_amdgcn_mfma_f32_32x32x16_bf16(kf[2], qf[2], scN, 0, 0, 0);
    scN = __builtin_amdgcn_mfma_f32_32x32x16_bf16(kf[3], qf[3], scN, 0, 0, 0);
    __builtin_amdgcn_s_setprio(0);
  };

  auto sm_pv = [&](f32x16& scP, int tp) {
    float4 mv[4];
#pragma unroll
    for (int c = 0; c < 4; ++c)
      mv[c] = *(const float4*)(&Ms[tp * 32 + c * 8 + 4 * hi]);
    const char* Vbuf = (const char*)(&Vs[(cur + 3) & 3][0]);
    const bf16x8 v00 = *(const bf16x8*)(Vbuf + l31 * 64 + ((hi ^ vsw) * 16));
    const bf16x8 v01 = *(const bf16x8*)(Vbuf + l31 * 64 + (((2 + hi) ^ vsw) * 16));
    const bf16x8 v10 = *(const bf16x8*)(Vbuf + (32 + l31) * 64 + ((hi ^ vsw) * 16));
    const bf16x8 v11 = *(const bf16x8*)(Vbuf + (32 + l31) * 64 + (((2 + hi) ^ vsw) * 16));
    float p[16];
    p[0] = exp2f(scP[0] * KSCALE + mv[0].x);  p[1] = exp2f(scP[1] * KSCALE + mv[0].y);
    p[2] = exp2f(scP[2] * KSCALE + mv[0].z);  p[3] = exp2f(scP[3] * KSCALE + mv[0].w);
    p[4] = exp2f(scP[4] * KSCALE + mv[1].x);  p[5] = exp2f(scP[5] * KSCALE + mv[1].y);
    p[6] = exp2f(scP[6] * KSCALE + mv[1].z);  p[7] = exp2f(scP[7] * KSCALE + mv[1].w);
    p[8] = exp2f(scP[8] * KSCALE + mv[2].x);  p[9] = exp2f(scP[9] * KSCALE + mv[2].y);
    p[10] = exp2f(scP[10] * KSCALE + mv[2].z); p[11] = exp2f(scP[11] * KSCALE + mv[2].w);
    p[12] = exp2f(scP[12] * KSCALE + mv[3].x); p[13] = exp2f(scP[13] * KSCALE + mv[3].y);
    p[14] = exp2f(scP[14] * KSCALE + mv[3].z); p[15] = exp2f(scP[15] * KSCALE + mv[3].w);
    unsigned cw[4][2];
#pragma unroll
    for (int a = 0; a < 4; ++a) {
      cw[a][0] = cvtpk_bf16(p[4 * a + 0], p[4 * a + 1]);
      cw[a][1] = cvtpk_bf16(p[4 * a + 2], p[4 * a + 3]);
    }
    unsigned a00 = cw[0][0], b00 = cw[1][0]; swapl(a00, b00);
    unsigned a01 = cw[0][1], b01 = cw[1][1]; swapl(a01, b01);
    unsigned a10 = cw[2][0], b10 = cw[3][0]; swapl(a10, b10);
    unsigned a11 = cw[2][1], b11 = cw[3][1]; swapl(a11, b11);
    union { unsigned u[4]; bf16x8 v; } pa0, pa1;
    pa0.u[0] = a00; pa0.u[1] = a01; pa0.u[2] = b00; pa0.u[3] = b01;
    pa1.u[0] = a10; pa1.u[1] = a11; pa1.u[2] = b10; pa1.u[3] = b11;
    __builtin_amdgcn_s_setprio(1);
    accA = __builtin_amdgcn_mfma_f32_32x32x16_bf16(pa0.v, v00, accA, 0, 0, 0);
    accA = __builtin_amdgcn_mfma_f32_32x32x16_bf16(pa1.v, v01, accA, 0, 0, 0);
    accB = __builtin_amdgcn_mfma_f32_32x32x16_bf16(pa0.v, v10, accB, 0, 0, 0);
    accB = __builtin_amdgcn_mfma_f32_32x32x16_bf16(pa1.v, v11, accB, 0, 0, 0);
    accS = __builtin_amdgcn_mfma_f32_32x32x16_bf16(pa0.v, ones, accS, 0, 0, 0);
    accS = __builtin_amdgcn_mfma_f32_32x32x16_bf16(pa1.v, ones, accS, 0, 0, 0);
    __builtin_amdgcn_s_setprio(0);
  };

  asm volatile("s_waitcnt vmcnt(1)" ::: "memory");
  asm volatile("s_barrier" ::: "memory");
  qk_phase(scA, 0);
  cur = 1;
  int t = 1;
  for (; t + 1 < nt; t += 2) {
    asm volatile("s_waitcnt vmcnt(1)" ::: "memory");
    asm volatile("s_barrier" ::: "memory");
    qk_phase(scB, t);
    sm_pv(scA, t - 1);
    cur = (cur + 1) & 3;
    asm volatile("s_waitcnt vmcnt(1)" ::: "memory");
    asm volatile("s_barrier" ::: "memory");
    qk_phase(scA, t + 1);
    sm_pv(scB, t);
    cur = (cur + 1) & 3;
  }
  if (t < nt) {
    asm volatile("s_waitcnt vmcnt(1)" ::: "memory");
    asm volatile("s_barrier" ::: "memory");
    qk_phase(scB, t);
    sm_pv(scA, t - 1);
    cur = (cur + 1) & 3;
    asm volatile("s_waitcnt vmcnt(0)" ::: "memory");
    sm_pv(scB, t);
  } else {
    asm volatile("s_waitcnt vmcnt(0)" ::: "memory");
    sm_pv(scA, nt - 1);
  }

#pragma unroll
  for (int r = 0; r < 16; ++r) {
    const int q = (r & 3) + 8 * (r >> 2) + 4 * hi;
    const float inv = rcpf(accS[r]);
    ushort_t* op = Ob + (bS + qrow0 + q) * Dc + h * DKc + l31;
    op[0] = f2bf(accA[r] * inv);
    op[32] = f2bf(accB[r] * inv);
  }
}

// ---------------- launcher ----------------
extern "C" void kernel_launch(void* const* d_in, const int* in_sizes, int n_in,
                              void* d_out, int out_size, void* d_ws, size_t ws_size,
                              hipStream_t stream) {
  const float* x     = (const float*)d_in[0];
  const int* mask    = (const int*)d_in[1];
  const float* wq_w  = (const float*)d_in[2];
  const float* wq_b  = (const float*)d_in[3];
  const float* wk_w  = (const float*)d_in[4];
  const float* wk_b  = (const float*)d_in[5];
  const float* wv_w  = (const float*)d_in[6];
  const float* wv_b  = (const float*)d_in[7];
  const float* wo_w  = (const float*)d_in[8];
  const float* wo_b  = (const float*)d_in[9];
  const float* ff_w0 = (const float*)d_in[10];
  const float* ff_b0 = (const float*)d_in[11];
  const float* ff_w1 = (const float*)d_in[12];
  const float* ff_b1 = (const float*)d_in[13];
  const float* ln0_a = (const float*)d_in[14];
  const float* ln0_b = (const float*)d_in[15];
  const float* ln1_a = (const float*)d_in[16];
  const float* ln1_b = (const float*)d_in[17];
  float* out = (float*)d_out;

  char* ws = (char*)d_ws;
  size_t off = 0;
  ushort_t* WTq = (ushort_t*)(ws + off); off += (size_t)Dc * Dc * 2;   // [3072,1024] packed
  ushort_t* WTk = (ushort_t*)(ws + off); off += (size_t)Dc * Dc * 2;
  ushort_t* WTv = (ushort_t*)(ws + off); off += (size_t)Dc * Dc * 2;
  ushort_t* WTo = (ushort_t*)(ws + off); off += (size_t)Dc * Dc * 2;
  ushort_t* WT0 = (ushort_t*)(ws + off); off += (size_t)DFFc * Dc * 2;
  ushort_t* WT1 = (ushort_t*)(ws + off); off += (size_t)Dc * DFFc * 2;
  ushort_t* hbuf = (ushort_t*)(ws + off); off += (size_t)Mc * Dc * 2;
  ushort_t* qbuf = (ushort_t*)(ws + off); off += (size_t)Mc * Dc * 2;
  ushort_t* kbuf = (ushort_t*)(ws + off); off += (size_t)Mc * Dc * 2;
  ushort_t* vtb  = (ushort_t*)(ws + off); off += (size_t)Mc * Dc * 2;  // Vt compacted
  ushort_t* abuf = (ushort_t*)(ws + off); off += (size_t)Mc * Dc * 2;
  float* maddb   = (float*)(ws + off);   off += (size_t)Bc * Sc * 4;   // compacted madd
  int* cidxb     = (int*)(ws + off);     off += (size_t)Mc * 4;
  int* ntileb    = (int*)(ws + off);     off += 64;
  ushort_t* gbuf = qbuf;  // overlays dead q/k/vt buffers

  const dim3 blk(256);
  const dim3 blk512(512);
  k_transpose_cvt<<<dim3(Dc / 32, Dc / 32), blk, 0, stream>>>(wq_w, WTq, Dc, Dc);
  k_transpose_cvt<<<dim3(Dc / 32, Dc / 32), blk, 0, stream>>>(wk_w, WTk, Dc, Dc);
  k_transpose_cvt<<<dim3(Dc / 32, Dc / 32), blk, 0, stream>>>(wv_w, WTv, Dc, Dc);
  k_transpose_cvt<<<dim3(Dc / 32, Dc / 32), blk, 0, stream>>>(wo_w, WTo, Dc, Dc);
  k_transpose_cvt<<<dim3(DFFc / 32, Dc / 32), blk, 0, stream>>>(ff_w0, WT0, Dc, DFFc);
  k_transpose_cvt<<<dim3(Dc / 32, DFFc / 32), blk, 0, stream>>>(ff_w1, WT1, DFFc, Dc);
  k_compact<<<dim3(Bc), blk, 0, stream>>>(mask, cidxb, maddb, ntileb);
  // LN0
  k_layernorm<<<Mc, blk, 0, stream>>>(x, ln0_a, ln0_b, hbuf);
  // fused QKV projection (K/V written compacted via cidx)
  k_gemm8<4><<<dim3(768), blk512, 0, stream>>>(hbuf, WTq, wq_b, wk_b, wv_b, nullptr,
                                               cidxb, qbuf, kbuf, vtb, 3072, Dc, 3);
  // attention over compacted keys
  k_attn12<<<dim3(512), blk512, 0, stream>>>(qbuf, kbuf, vtb, maddb, ntileb, abuf);
  // O projection + residual(x) -> d_out (f32): deep 4-buffer pipeline
  k_gemm8d<<<dim3(256), blk512, 0, stream>>>(abuf, WTo, wo_b, x, out, Dc, Dc);
  // LN1
  k_layernorm<<<Mc, blk, 0, stream>>>(out, ln1_a, ln1_b, hbuf);
  // FFN0 + sigmoid-GELU -> gbuf (bf16)
  k_gemm8<2><<<dim3(1024), blk512, 0, stream>>>(hbuf, WT0, ff_b0, nullptr, nullptr, nullptr,
                                                nullptr, gbuf, nullptr, nullptr, DFFc, Dc, 4);
  // FFN1 + residual(d_out) -> d_out (f32): deep 4-buffer pipeline
  k_gemm8d<<<dim3(256), blk512, 0, stream>>>(gbuf, WT1, ff_b1, out, out, Dc, DFFc);
}